// Round 1
// baseline (560.558 us; speedup 1.0000x reference)
//
#include <hip/hip_runtime.h>
#include <hip/hip_bf16.h>

#define B_ 4
#define T_ 4096
#define C_ 1024
#define H_ 64

__device__ __forceinline__ float rlane(float v, int lane) {
    return __uint_as_float((unsigned)__builtin_amdgcn_readlane(__float_as_uint(v), lane));
}

// ---------------------------------------------------------------------------
// Kernel 1: fused QKV projection.  x:[B*T, C]  W*:[C, H]  ->  Q/K/V:[B*T, H]
// Block = 256 threads, tile = 16 rows of x staged in LDS (64 KiB).
// thread t: h = t&63 (coalesced W reads), rg = t>>6 owns 4 rows.
// ---------------------------------------------------------------------------
__global__ __launch_bounds__(256) void qkv_proj(
    const float* __restrict__ x,  const float* __restrict__ Wq,
    const float* __restrict__ Wk, const float* __restrict__ Wv,
    float* __restrict__ Q, float* __restrict__ K, float* __restrict__ V)
{
    __shared__ float xs[16 * C_];                     // 64 KiB
    const int t = threadIdx.x;
    const size_t rowbase = (size_t)blockIdx.x * 16;

    // cooperative load: 16*1024 floats = 4096 float4, 16 per thread
    const float4* xg  = (const float4*)(x + rowbase * C_);
    float4*       xs4 = (float4*)xs;
    #pragma unroll
    for (int u = 0; u < 16; ++u) xs4[t + u * 256] = xg[t + u * 256];
    __syncthreads();

    const int h  = t & 63;
    const int rg = t >> 6;                            // 0..3
    float aq[4] = {0,0,0,0}, ak[4] = {0,0,0,0}, av[4] = {0,0,0,0};
    #pragma unroll 4
    for (int c = 0; c < C_; ++c) {
        const float wq = Wq[c * H_ + h];
        const float wk = Wk[c * H_ + h];
        const float wv = Wv[c * H_ + h];
        #pragma unroll
        for (int r = 0; r < 4; ++r) {
            const float xv = xs[(rg * 4 + r) * C_ + c];   // wave-uniform broadcast
            aq[r] = fmaf(xv, wq, aq[r]);
            ak[r] = fmaf(xv, wk, ak[r]);
            av[r] = fmaf(xv, wv, av[r]);
        }
    }
    #pragma unroll
    for (int r = 0; r < 4; ++r) {
        const size_t o = (rowbase + rg * 4 + r) * H_ + h;
        Q[o] = aq[r]; K[o] = ak[r]; V[o] = av[r];
    }
}

// ---------------------------------------------------------------------------
// Kernel 2: causal flash attention, fp32 vector ALU.
// BQ=32 q-rows per tile, BK=64 k-cols per tile. 512 threads = 8 waves,
// each wave owns 4 q-rows. lane = k-column (S phase) and head-dim (PV phase).
// Q rows and the P tile live in registers; A-operand broadcast via v_readlane.
// Block g processes q-tiles {g, 127-g} -> constant 65 k-tile iters (balance).
// LDS rows padded to 65 floats: bank = (row + col) % 32, conflict-free.
// ---------------------------------------------------------------------------
#define BQ 32
#define BK 64
#define RW 4   // q-rows per wave

__global__ __launch_bounds__(512) void attn(
    const float* __restrict__ Q, const float* __restrict__ K,
    const float* __restrict__ V, float* __restrict__ out)
{
    __shared__ float Ks[BK][H_ + 1];
    __shared__ float Vs[BK][H_ + 1];
    const int tid  = threadIdx.x;
    const int lane = tid & 63;
    const int w    = tid >> 6;                        // 0..7
    const int b    = blockIdx.y;
    const float scale = 0.125f;                       // 1/sqrt(64)

    #pragma unroll 1
    for (int pass = 0; pass < 2; ++pass) {
        const int qt    = (pass == 0) ? (int)blockIdx.x : (127 - (int)blockIdx.x);
        const int qrow0 = qt * BQ + w * RW;           // first global q-row of wave

        float qreg[RW];
        const float* Qb = Q + ((size_t)b * T_ + qrow0) * H_;
        #pragma unroll
        for (int i = 0; i < RW; ++i) qreg[i] = Qb[i * H_ + lane] * scale;

        float m[RW], l[RW], o[RW];
        #pragma unroll
        for (int i = 0; i < RW; ++i) { m[i] = -1e30f; l[i] = 0.f; o[i] = 0.f; }

        const int nk = qt / 2 + 1;                    // ceil((qt+1)/2) 64-wide tiles
        for (int kt = 0; kt < nk; ++kt) {
            __syncthreads();                          // previous tile fully consumed
            const float4* Kg = (const float4*)(K + ((size_t)b * T_ + kt * BK) * H_);
            const float4* Vg = (const float4*)(V + ((size_t)b * T_ + kt * BK) * H_);
            #pragma unroll
            for (int u = 0; u < 2; ++u) {
                const int f = tid + u * 512;          // 0..1023 float4s
                const float4 k4 = Kg[f];
                const float4 v4 = Vg[f];
                const int r = f >> 4, cc = (f & 15) * 4;
                Ks[r][cc] = k4.x; Ks[r][cc+1] = k4.y; Ks[r][cc+2] = k4.z; Ks[r][cc+3] = k4.w;
                Vs[r][cc] = v4.x; Vs[r][cc+1] = v4.y; Vs[r][cc+2] = v4.z; Vs[r][cc+3] = v4.w;
            }
            __syncthreads();

            // S[i][lane] = (q_i . k_lane) * scale   (q pre-scaled)
            float p[RW] = {0.f, 0.f, 0.f, 0.f};
            #pragma unroll
            for (int c0 = 0; c0 < H_; c0 += 8) {
                float kreg[8];
                #pragma unroll
                for (int c = 0; c < 8; ++c) kreg[c] = Ks[lane][c0 + c];
                #pragma unroll
                for (int i = 0; i < RW; ++i)
                    #pragma unroll
                    for (int c = 0; c < 8; ++c)
                        p[i] = fmaf(rlane(qreg[i], c0 + c), kreg[c], p[i]);
            }

            // causal mask (exact condition; no-op on interior tiles)
            const int s = kt * BK + lane;
            #pragma unroll
            for (int i = 0; i < RW; ++i)
                if (s > qrow0 + i) p[i] = -1e30f;

            // online softmax across the 64 lanes (per row)
            #pragma unroll
            for (int i = 0; i < RW; ++i) {
                float mx = p[i];
                #pragma unroll
                for (int off = 32; off > 0; off >>= 1)
                    mx = fmaxf(mx, __shfl_xor(mx, off, 64));
                const float mn    = fmaxf(m[i], mx);
                const float alpha = __expf(m[i] - mn);
                p[i] = __expf(p[i] - mn);
                float sm = p[i];
                #pragma unroll
                for (int off = 32; off > 0; off >>= 1)
                    sm += __shfl_xor(sm, off, 64);
                l[i] = l[i] * alpha + sm;
                o[i] *= alpha;
                m[i] = mn;
            }

            // o[i][h=lane] += sum_j p[i][j] * V[j][lane]
            #pragma unroll
            for (int j0 = 0; j0 < BK; j0 += 8) {
                float vreg[8];
                #pragma unroll
                for (int j = 0; j < 8; ++j) vreg[j] = Vs[j0 + j][lane];
                #pragma unroll
                for (int i = 0; i < RW; ++i)
                    #pragma unroll
                    for (int j = 0; j < 8; ++j)
                        o[i] = fmaf(rlane(p[i], j0 + j), vreg[j], o[i]);
            }
        }

        float* Ob = out + ((size_t)b * T_ + qrow0) * H_;
        #pragma unroll
        for (int i = 0; i < RW; ++i)
            Ob[i * H_ + lane] = o[i] / l[i];
        // next pass's first __syncthreads() protects LDS reuse
    }
}

extern "C" void kernel_launch(void* const* d_in, const int* in_sizes, int n_in,
                              void* d_out, int out_size, void* d_ws, size_t ws_size,
                              hipStream_t stream) {
    const float* x  = (const float*)d_in[0];
    const float* Wq = (const float*)d_in[1];
    const float* Wk = (const float*)d_in[2];
    const float* Wv = (const float*)d_in[3];
    float* out = (float*)d_out;

    float* ws = (float*)d_ws;
    const size_t NE = (size_t)B_ * T_ * H_;           // 1,048,576 elements (4 MiB)
    float* Qp = ws;
    float* Kp = ws + NE;
    float* Vp = ws + 2 * NE;

    hipLaunchKernelGGL(qkv_proj, dim3((B_ * T_) / 16), dim3(256), 0, stream,
                       x, Wq, Wk, Wv, Qp, Kp, Vp);
    hipLaunchKernelGGL(attn, dim3(T_ / BQ / 2, B_), dim3(512), 0, stream,
                       Qp, Kp, Vp, out);
}

// Round 2
// 330.059 us; speedup vs baseline: 1.6984x; 1.6984x over previous
//
#include <hip/hip_runtime.h>

#define B_ 4
#define T_ 4096
#define C_ 1024
#define H_ 64

typedef _Float16 half8  __attribute__((ext_vector_type(8)));
typedef _Float16 half4_ __attribute__((ext_vector_type(4)));
typedef float    floatx4 __attribute__((ext_vector_type(4)));

#define MFMA16(a, b, c) __builtin_amdgcn_mfma_f32_16x16x32_f16(a, b, c, 0, 0, 0)

// ---------------------------------------------------------------------------
// Kernel 1: pack W -> Wt[h'][c] f16, h' = 0..191 (q:0-63, k:64-127, v:128-191)
// ---------------------------------------------------------------------------
__global__ __launch_bounds__(256) void pack_w_kn(
    const float* __restrict__ Wq, const float* __restrict__ Wk,
    const float* __restrict__ Wv, _Float16* __restrict__ Wt)
{
    const int idx = blockIdx.x * 256 + threadIdx.x;   // 0 .. 192*1024-1
    const int hp = idx >> 10, c = idx & 1023;
    const float* W = (hp < 64) ? Wq : (hp < 128) ? Wk : Wv;
    Wt[idx] = (_Float16)W[c * H_ + (hp & 63)];
}

// ---------------------------------------------------------------------------
// Kernel 2: fused QKV projection via f16 MFMA.  C^T = Wt * x^T.
// Wave owns 16 x-rows. A-frag (Wt) and B-frag (x, cvt fp32->f16) loaded
// straight from global: A[m=lane&15][k=quad*8+j] contiguous in Wt,
// B[k=quad*8+j][n=lane&15] contiguous in x. x read exactly once (64 MB).
// Outputs: Qh,Kh row-major [B*T][64] f16;  Vt transposed [B][64][T] f16.
// ---------------------------------------------------------------------------
__global__ __launch_bounds__(256) void qkv_kn(
    const float* __restrict__ x, const _Float16* __restrict__ Wt,
    _Float16* __restrict__ Qh, _Float16* __restrict__ Kh,
    _Float16* __restrict__ Vt)
{
    const int lane = threadIdx.x & 63;
    const int w    = threadIdx.x >> 6;
    const int q    = lane >> 4, c = lane & 15;
    const int row  = blockIdx.x * 64 + w * 16 + c;    // lane's x-row (B-frag n, C col)

    const float*    xp = x  + (size_t)row * C_ + q * 8;
    const _Float16* wp = Wt + (size_t)c   * C_ + q * 8;

    floatx4 acc[12];
    #pragma unroll
    for (int i = 0; i < 12; ++i) acc[i] = floatx4{0.f, 0.f, 0.f, 0.f};

    #pragma unroll 2
    for (int ks = 0; ks < 32; ++ks) {
        const float4 f0 = *(const float4*)(xp + ks * 32);
        const float4 f1 = *(const float4*)(xp + ks * 32 + 4);
        half8 bx;
        bx[0] = (_Float16)f0.x; bx[1] = (_Float16)f0.y;
        bx[2] = (_Float16)f0.z; bx[3] = (_Float16)f0.w;
        bx[4] = (_Float16)f1.x; bx[5] = (_Float16)f1.y;
        bx[6] = (_Float16)f1.z; bx[7] = (_Float16)f1.w;
        #pragma unroll
        for (int mt = 0; mt < 12; ++mt) {
            const half8 a = *(const half8*)(wp + (size_t)mt * 16 * C_ + ks * 32);
            acc[mt] = MFMA16(a, bx, acc[mt]);
        }
    }

    // Epilogue. C^T layout: lane holds col = its row, rows h' = mt*16+q*4+r.
    const int b = row >> 12, t = row & (T_ - 1);
    #pragma unroll
    for (int mt = 0; mt < 4; ++mt) {                  // Q: h = mt*16+q*4+r
        half4_ v;
        #pragma unroll
        for (int r = 0; r < 4; ++r) v[r] = (_Float16)acc[mt][r];
        *(half4_*)(Qh + (size_t)row * H_ + mt * 16 + q * 4) = v;
    }
    #pragma unroll
    for (int mt = 4; mt < 8; ++mt) {                  // K
        half4_ v;
        #pragma unroll
        for (int r = 0; r < 4; ++r) v[r] = (_Float16)acc[mt][r];
        *(half4_*)(Kh + (size_t)row * H_ + (mt - 4) * 16 + q * 4) = v;
    }
    #pragma unroll
    for (int mt = 8; mt < 12; ++mt)                   // V transposed: Vt[b][h][t]
        #pragma unroll
        for (int r = 0; r < 4; ++r) {
            const int h2 = (mt - 8) * 16 + q * 4 + r;
            Vt[((size_t)b * H_ + h2) * T_ + t] = (_Float16)acc[mt][r];
        }
}

// ---------------------------------------------------------------------------
// Kernel 3: causal flash attention, f16 MFMA, one wave = 16 q-rows, no
// barriers.  S^T = K·Q^T  (C-layout -> per-q-row softmax is in-lane + 2
// shuffles).  P^T -> wave-private LDS (row-major [qrow][key], pad 72) ->
// B-frags for O^T = V^T·P^T.  All global operands 16B contiguous (L2-served).
// ---------------------------------------------------------------------------
__global__ __launch_bounds__(256) void attn_kn(
    const _Float16* __restrict__ Qh, const _Float16* __restrict__ Kh,
    const _Float16* __restrict__ Vt, float* __restrict__ out)
{
    __shared__ _Float16 Pl[4][16 * 72];
    const int lane = threadIdx.x & 63;
    const int w    = threadIdx.x >> 6;
    const int q    = lane >> 4, c = lane & 15;
    const int b    = blockIdx.y;
    const int g    = blockIdx.x * 4 + w;              // 16-row tile idx in batch
    const int row0 = g * 16;
    const int grow = b * T_ + row0;

    const _Float16* Kb = Kh + (size_t)b * T_ * H_;
    const _Float16* Vb = Vt + (size_t)b * H_ * T_;
    _Float16* pl = Pl[w] + c * 72;                    // lane's P row (its q-row)

    // Q B-frag: B[k=h][n=qrow], 8 consecutive h. Pre-scale by 1/8 * log2(e).
    half8 bq0 = *(const half8*)(Qh + (size_t)(grow + c) * H_ + q * 8);
    half8 bq1 = *(const half8*)(Qh + (size_t)(grow + c) * H_ + 32 + q * 8);
    const _Float16 qs = (_Float16)0.18033688f;
    bq0 *= qs; bq1 *= qs;

    floatx4 o[4];
    #pragma unroll
    for (int i = 0; i < 4; ++i) o[i] = floatx4{0.f, 0.f, 0.f, 0.f};
    float m = -3.0e38f, l = 0.f;

    const int nfull = g >> 2;                         // iters before the masked one
    for (int kt = 0; kt <= nfull; ++kt) {
        const int kb = kt * 64;

        // S^T tiles: rows = keys (4 tiles of 16), col = q-row (in-lane).
        floatx4 s[4];
        #pragma unroll
        for (int mt = 0; mt < 4; ++mt) {
            const _Float16* kp = Kb + (size_t)(kb + mt * 16 + c) * H_ + q * 8;
            const half8 a0 = *(const half8*)kp;
            const half8 a1 = *(const half8*)(kp + 32);
            floatx4 z = floatx4{0.f, 0.f, 0.f, 0.f};
            z = MFMA16(a0, bq0, z);
            s[mt] = MFMA16(a1, bq1, z);
        }

        if (kt == nfull) {                            // causal mask (diagonal tile)
            #pragma unroll
            for (int mt = 0; mt < 4; ++mt)
                #pragma unroll
                for (int r = 0; r < 4; ++r)
                    if (kb + mt * 16 + q * 4 + r > row0 + c) s[mt][r] = -3.0e38f;
        }

        // online softmax; lane holds 16 scores of ONE q-row; full row spans
        // the 4 quads -> 2 xor-shuffles finish the reduction.
        float mx = s[0][0];
        #pragma unroll
        for (int mt = 0; mt < 4; ++mt)
            #pragma unroll
            for (int r = 0; r < 4; ++r) mx = fmaxf(mx, s[mt][r]);
        mx = fmaxf(mx, __shfl_xor(mx, 16, 64));
        mx = fmaxf(mx, __shfl_xor(mx, 32, 64));
        const float mn    = fmaxf(m, mx);
        const float alpha = exp2f(m - mn);
        float p[4][4];
        float sl = 0.f;
        #pragma unroll
        for (int mt = 0; mt < 4; ++mt)
            #pragma unroll
            for (int r = 0; r < 4; ++r) {
                p[mt][r] = exp2f(s[mt][r] - mn);
                sl += p[mt][r];
            }
        sl += __shfl_xor(sl, 16, 64);
        sl += __shfl_xor(sl, 32, 64);
        l = l * alpha + sl;
        m = mn;
        #pragma unroll
        for (int mt = 0; mt < 4; ++mt)
            #pragma unroll
            for (int r = 0; r < 4; ++r) o[mt][r] *= alpha;

        // P^T -> LDS row c (keys mt*16+q*4..+3 contiguous -> b64 writes)
        #pragma unroll
        for (int mt = 0; mt < 4; ++mt) {
            half4_ ph;
            #pragma unroll
            for (int r = 0; r < 4; ++r) ph[r] = (_Float16)p[mt][r];
            *(half4_*)(pl + mt * 16 + q * 4) = ph;
        }
        // wave-private LDS: order write->read with lgkm drain (no barrier)
        asm volatile("s_waitcnt lgkmcnt(0)" ::: "memory");
        const half8 bp0 = *(const half8*)(pl + q * 8);
        const half8 bp1 = *(const half8*)(pl + 32 + q * 8);

        // O^T += V^T · P^T   (A-frag contiguous from Vt[h][t])
        #pragma unroll
        for (int mt = 0; mt < 4; ++mt) {
            const _Float16* vp = Vb + (size_t)(mt * 16 + c) * T_ + kb + q * 8;
            const half8 a0 = *(const half8*)vp;
            const half8 a1 = *(const half8*)(vp + 32);
            o[mt] = MFMA16(a0, bp0, o[mt]);
            o[mt] = MFMA16(a1, bp1, o[mt]);
        }
        asm volatile("" ::: "memory");                // keep next writes after reads
    }

    // epilogue: lane owns q-row c of the tile; h = mt*16+q*4+r consecutive.
    const float inv = 1.f / l;
    float* op = out + (size_t)(grow + c) * H_;
    #pragma unroll
    for (int mt = 0; mt < 4; ++mt) {
        float4 st;
        st.x = o[mt][0] * inv; st.y = o[mt][1] * inv;
        st.z = o[mt][2] * inv; st.w = o[mt][3] * inv;
        *(float4*)(op + mt * 16 + q * 4) = st;
    }
}

extern "C" void kernel_launch(void* const* d_in, const int* in_sizes, int n_in,
                              void* d_out, int out_size, void* d_ws, size_t ws_size,
                              hipStream_t stream) {
    const float* x  = (const float*)d_in[0];
    const float* Wq = (const float*)d_in[1];
    const float* Wk = (const float*)d_in[2];
    const float* Wv = (const float*)d_in[3];
    float* out = (float*)d_out;

    _Float16* ws = (_Float16*)d_ws;
    _Float16* Wt = ws;                                //   192*1024 = 196608
    _Float16* Qh = ws + 196608;                       // 16384*64  = 1048576
    _Float16* Kh = Qh + 1048576;
    _Float16* Vt = Kh + 1048576;                      // [4][64][4096]

    hipLaunchKernelGGL(pack_w_kn, dim3(768), dim3(256), 0, stream, Wq, Wk, Wv, Wt);
    hipLaunchKernelGGL(qkv_kn, dim3((B_ * T_) / 64), dim3(256), 0, stream,
                       x, Wt, Qh, Kh, Vt);
    hipLaunchKernelGGL(attn_kn, dim3(T_ / 64, B_), dim3(256), 0, stream,
                       Qh, Kh, Vt, out);
}

// Round 3
// 233.943 us; speedup vs baseline: 2.3961x; 1.4109x over previous
//
#include <hip/hip_runtime.h>

#define B_ 4
#define T_ 4096
#define C_ 1024
#define H_ 64

typedef _Float16 half8  __attribute__((ext_vector_type(8)));
typedef _Float16 half4_ __attribute__((ext_vector_type(4)));
typedef float    floatx4 __attribute__((ext_vector_type(4)));

#define MFMA16(a, b, c) __builtin_amdgcn_mfma_f32_16x16x32_f16(a, b, c, 0, 0, 0)

// ---------------------------------------------------------------------------
// Kernel 1: pack W -> Wt[h'][c] f16, h' = 0..191 (q:0-63, k:64-127, v:128-191)
// ---------------------------------------------------------------------------
__global__ __launch_bounds__(256) void pack_w_kn(
    const float* __restrict__ Wq, const float* __restrict__ Wk,
    const float* __restrict__ Wv, _Float16* __restrict__ Wt)
{
    const int idx = blockIdx.x * 256 + threadIdx.x;   // 0 .. 192*1024-1
    const int hp = idx >> 10, c = idx & 1023;
    const float* W = (hp < 64) ? Wq : (hp < 128) ? Wk : Wv;
    Wt[idx] = (_Float16)W[c * H_ + (hp & 63)];
}

// ---------------------------------------------------------------------------
// Kernel 2: fused QKV projection, f16 MFMA, C^T = Wt * x^T.
// Block = 16 x-rows, 4 waves split 2x2 over (h'-half, C-half):
//   whalf = w&1 -> global mt in [whalf*6, whalf*6+6)
//   chalf = w>>1 -> C-range [chalf*512, +512), 16 K-steps of 32
// 4096 waves total = 16 waves/CU (TLP hides global-load latency).
// C-halves merged via LDS; x HBM-read once (h'-split re-read is L2-hit).
// ---------------------------------------------------------------------------
__global__ __launch_bounds__(256) void qkv_kn(
    const float* __restrict__ x, const _Float16* __restrict__ Wt,
    _Float16* __restrict__ Qh, _Float16* __restrict__ Kh,
    _Float16* __restrict__ Vt)
{
    __shared__ float Aw[2][64][24];                   // 12 KiB: chalf=1 partials
    const int lane  = threadIdx.x & 63;
    const int w     = threadIdx.x >> 6;
    const int whalf = w & 1;
    const int chalf = w >> 1;
    const int q     = lane >> 4, c = lane & 15;
    const int row   = blockIdx.x * 16 + c;            // lane's x-row (B-frag n)

    const float*    xp = x  + (size_t)row * C_ + chalf * 512 + q * 8;
    const _Float16* wp = Wt + (size_t)(whalf * 6 * 16 + c) * C_ + chalf * 512 + q * 8;

    floatx4 acc[6];
    #pragma unroll
    for (int i = 0; i < 6; ++i) acc[i] = floatx4{0.f, 0.f, 0.f, 0.f};

    #pragma unroll 2
    for (int ks = 0; ks < 16; ++ks) {
        const float4 f0 = *(const float4*)(xp + ks * 32);
        const float4 f1 = *(const float4*)(xp + ks * 32 + 4);
        half8 bx;
        bx[0] = (_Float16)f0.x; bx[1] = (_Float16)f0.y;
        bx[2] = (_Float16)f0.z; bx[3] = (_Float16)f0.w;
        bx[4] = (_Float16)f1.x; bx[5] = (_Float16)f1.y;
        bx[6] = (_Float16)f1.z; bx[7] = (_Float16)f1.w;
        #pragma unroll
        for (int mt = 0; mt < 6; ++mt) {
            const half8 a = *(const half8*)(wp + (size_t)mt * 16 * C_ + ks * 32);
            acc[mt] = MFMA16(a, bx, acc[mt]);
        }
    }

    // merge C-halves: chalf=1 writes partials, chalf=0 sums + epilogue
    if (chalf == 1) {
        #pragma unroll
        for (int mt = 0; mt < 6; ++mt)
            *(floatx4*)&Aw[whalf][lane][mt * 4] = acc[mt];
    }
    __syncthreads();
    if (chalf == 0) {
        #pragma unroll
        for (int mt = 0; mt < 6; ++mt)
            acc[mt] += *(const floatx4*)&Aw[whalf][lane][mt * 4];

        const int b = row >> 12, t = row & (T_ - 1);
        #pragma unroll
        for (int mt = 0; mt < 6; ++mt) {
            const int g = whalf * 6 + mt;             // global mt 0..11
            if (g < 4) {                              // Q: h = g*16+q*4+r
                half4_ v;
                #pragma unroll
                for (int r = 0; r < 4; ++r) v[r] = (_Float16)acc[mt][r];
                *(half4_*)(Qh + (size_t)row * H_ + g * 16 + q * 4) = v;
            } else if (g < 8) {                       // K
                half4_ v;
                #pragma unroll
                for (int r = 0; r < 4; ++r) v[r] = (_Float16)acc[mt][r];
                *(half4_*)(Kh + (size_t)row * H_ + (g - 4) * 16 + q * 4) = v;
            } else {                                  // V transposed: Vt[b][h][t]
                #pragma unroll
                for (int r = 0; r < 4; ++r) {
                    const int h2 = (g - 8) * 16 + q * 4 + r;
                    Vt[((size_t)b * H_ + h2) * T_ + t] = (_Float16)acc[mt][r];
                }
            }
        }
    }
}

// ---------------------------------------------------------------------------
// Kernel 3: causal flash attention, f16 MFMA, split-K across the block's 4
// waves.  Block = one 16-row q-tile; wave w handles key-tiles w, w+4, ...
// (balanced +-1 under causal).  Partial (m, l, O) merged via LDS flash
// combine.  Grid (256,4) = 1024 blocks = 16 waves/CU.
// ---------------------------------------------------------------------------
__global__ __launch_bounds__(256) void attn_kn(
    const _Float16* __restrict__ Qh, const _Float16* __restrict__ Kh,
    const _Float16* __restrict__ Vt, float* __restrict__ out)
{
    __shared__ _Float16 Pl[4][16 * 72];               //  9216 B (wave-private P)
    __shared__ float Ol[4][1088];                     // 17408 B: [w][h*17 + c]
    __shared__ float Ml[4][16], Ll[4][16];            //   512 B
    const int lane = threadIdx.x & 63;
    const int w    = threadIdx.x >> 6;
    const int q    = lane >> 4, c = lane & 15;
    const int b    = blockIdx.y;
    const int t    = blockIdx.x;                      // 16-row q-tile in batch
    const int row0 = t * 16;
    const int grow = b * T_ + row0;
    const int nk   = (t >> 2) + 1;                    // 64-key tiles (last = diag)

    const _Float16* Kb = Kh + (size_t)b * T_ * H_;
    const _Float16* Vb = Vt + (size_t)b * H_ * T_;
    _Float16* pl = Pl[w] + c * 72;                    // lane's P row (its q-row)

    // Q B-frag: B[k=h][n=qrow].  Pre-scale by (1/8)*log2(e).
    half8 bq0 = *(const half8*)(Qh + (size_t)(grow + c) * H_ + q * 8);
    half8 bq1 = *(const half8*)(Qh + (size_t)(grow + c) * H_ + 32 + q * 8);
    const _Float16 qs = (_Float16)0.18033688f;
    bq0 *= qs; bq1 *= qs;

    floatx4 o[4];
    #pragma unroll
    for (int i = 0; i < 4; ++i) o[i] = floatx4{0.f, 0.f, 0.f, 0.f};
    float m = -3.0e38f, l = 0.f;

    for (int kt = w; kt < nk; kt += 4) {
        const int kb = kt * 64;

        // S^T tiles: rows = keys (4 tiles of 16), col = q-row (in-lane)
        floatx4 s[4];
        #pragma unroll
        for (int mt = 0; mt < 4; ++mt) {
            const _Float16* kp = Kb + (size_t)(kb + mt * 16 + c) * H_ + q * 8;
            const half8 a0 = *(const half8*)kp;
            const half8 a1 = *(const half8*)(kp + 32);
            floatx4 z = floatx4{0.f, 0.f, 0.f, 0.f};
            z = MFMA16(a0, bq0, z);
            s[mt] = MFMA16(a1, bq1, z);
        }

        if (kt == nk - 1) {                           // causal mask (diag tile)
            #pragma unroll
            for (int mt = 0; mt < 4; ++mt)
                #pragma unroll
                for (int r = 0; r < 4; ++r)
                    if (kb + mt * 16 + q * 4 + r > row0 + c) s[mt][r] = -3.0e38f;
        }

        // online softmax; lane holds 16 scores of ONE q-row (spread over quads)
        float mx = s[0][0];
        #pragma unroll
        for (int mt = 0; mt < 4; ++mt)
            #pragma unroll
            for (int r = 0; r < 4; ++r) mx = fmaxf(mx, s[mt][r]);
        mx = fmaxf(mx, __shfl_xor(mx, 16, 64));
        mx = fmaxf(mx, __shfl_xor(mx, 32, 64));
        const float mn    = fmaxf(m, mx);
        const float alpha = exp2f(m - mn);
        float p[4][4];
        float sl = 0.f;
        #pragma unroll
        for (int mt = 0; mt < 4; ++mt)
            #pragma unroll
            for (int r = 0; r < 4; ++r) {
                p[mt][r] = exp2f(s[mt][r] - mn);
                sl += p[mt][r];
            }
        sl += __shfl_xor(sl, 16, 64);
        sl += __shfl_xor(sl, 32, 64);
        l = l * alpha + sl;
        m = mn;
        #pragma unroll
        for (int mt = 0; mt < 4; ++mt)
            #pragma unroll
            for (int r = 0; r < 4; ++r) o[mt][r] *= alpha;

        // P^T -> wave-private LDS row c, then reload as B-frags
        #pragma unroll
        for (int mt = 0; mt < 4; ++mt) {
            half4_ ph;
            #pragma unroll
            for (int r = 0; r < 4; ++r) ph[r] = (_Float16)p[mt][r];
            *(half4_*)(pl + mt * 16 + q * 4) = ph;
        }
        asm volatile("s_waitcnt lgkmcnt(0)" ::: "memory");
        const half8 bp0 = *(const half8*)(pl + q * 8);
        const half8 bp1 = *(const half8*)(pl + 32 + q * 8);

        // O^T += V^T · P^T   (A-frag contiguous from Vt[h][t])
        #pragma unroll
        for (int mt = 0; mt < 4; ++mt) {
            const _Float16* vp = Vb + (size_t)(mt * 16 + c) * T_ + kb + q * 8;
            const half8 a0 = *(const half8*)vp;
            const half8 a1 = *(const half8*)(vp + 32);
            o[mt] = MFMA16(a0, bp0, o[mt]);
            o[mt] = MFMA16(a1, bp1, o[mt]);
        }
        asm volatile("" ::: "memory");
    }

    // ---- flash combine across the 4 waves ----
    if (q == 0) Ml[w][c] = m;
    __syncthreads();
    const float M = fmaxf(fmaxf(Ml[0][c], Ml[1][c]),
                          fmaxf(Ml[2][c], Ml[3][c]));
    const float alpha = exp2f(m - M);                 // 0 for empty waves
    if (q == 0) Ll[w][c] = l * alpha;
    #pragma unroll
    for (int mt = 0; mt < 4; ++mt)
        #pragma unroll
        for (int r = 0; r < 4; ++r)
            Ol[w][(mt * 16 + q * 4 + r) * 17 + c] = o[mt][r] * alpha;
    __syncthreads();

    // wave w reduces h-range [w*16, w*16+16) for all 16 q-rows
    const float L = Ll[0][c] + Ll[1][c] + Ll[2][c] + Ll[3][c];
    const float inv = 1.f / L;
    float4 osum = make_float4(0.f, 0.f, 0.f, 0.f);
    const int hb = w * 16 + q * 4;
    #pragma unroll
    for (int w2 = 0; w2 < 4; ++w2) {
        osum.x += Ol[w2][(hb + 0) * 17 + c];
        osum.y += Ol[w2][(hb + 1) * 17 + c];
        osum.z += Ol[w2][(hb + 2) * 17 + c];
        osum.w += Ol[w2][(hb + 3) * 17 + c];
    }
    osum.x *= inv; osum.y *= inv; osum.z *= inv; osum.w *= inv;
    *(float4*)(out + (size_t)(grow + c) * H_ + hb) = osum;
}

extern "C" void kernel_launch(void* const* d_in, const int* in_sizes, int n_in,
                              void* d_out, int out_size, void* d_ws, size_t ws_size,
                              hipStream_t stream) {
    const float* x  = (const float*)d_in[0];
    const float* Wq = (const float*)d_in[1];
    const float* Wk = (const float*)d_in[2];
    const float* Wv = (const float*)d_in[3];
    float* out = (float*)d_out;

    _Float16* ws = (_Float16*)d_ws;
    _Float16* Wt = ws;                                //   192*1024 = 196608
    _Float16* Qh = ws + 196608;                       // 16384*64  = 1048576
    _Float16* Kh = Qh + 1048576;
    _Float16* Vt = Kh + 1048576;                      // [4][64][4096]

    hipLaunchKernelGGL(pack_w_kn, dim3(768), dim3(256), 0, stream, Wq, Wk, Wv, Wt);
    hipLaunchKernelGGL(qkv_kn, dim3((B_ * T_) / 16), dim3(256), 0, stream,
                       x, Wt, Qh, Kh, Vt);
    hipLaunchKernelGGL(attn_kn, dim3(T_ / 16, B_), dim3(256), 0, stream,
                       Qh, Kh, Vt, out);
}